// Round 1
// baseline (79.806 us; speedup 1.0000x reference)
//
#include <hip/hip_runtime.h>
#include <hip/hip_bf16.h>

#define B_ 32
#define L_ 512
#define H_ 1024
#define E_ 8
#define R_ 16

// ---------------- gates: logits = x[:,0,:] @ router_w^T ; top-2 softmax ----
__global__ __launch_bounds__(256) void moe_gates_kernel(
    const float* __restrict__ x, const float* __restrict__ rw,
    float* __restrict__ gws)
{
  const int b = blockIdx.x;
  const int t = threadIdx.x;
  const int e = t >> 5;        // 8 experts
  const int s = t & 31;        // 32 lanes per expert
  const float* cls = x + (size_t)b * L_ * H_;   // x[b,0,:]
  const float* w   = rw + (size_t)e * H_;
  float p = 0.f;
  for (int h = s; h < H_; h += 32) p += cls[h] * w[h];
#pragma unroll
  for (int off = 16; off; off >>= 1) p += __shfl_down(p, off, 32);
  __shared__ float logits[E_];
  if (s == 0) logits[e] = p;
  __syncthreads();
  if (t == 0) {
    float m0 = -1e30f; int i0 = 0;
    for (int j = 0; j < E_; ++j) { if (logits[j] > m0) { m0 = logits[j]; i0 = j; } }
    float m1 = -1e30f; int i1 = 0;
    for (int j = 0; j < E_; ++j) { if (j != i0 && logits[j] > m1) { m1 = logits[j]; i1 = j; } }
    // softmax over {m0, m1} (all other gates are exactly 0)
    float eb = expf(m1 - m0);
    float inv = 1.f / (1.f + eb);
    gws[b * 4 + 0] = inv;          // gate for expert i0
    gws[b * 4 + 1] = eb * inv;     // gate for expert i1
    ((int*)gws)[b * 4 + 2] = i0;
    ((int*)gws)[b * 4 + 3] = i1;
  }
}

// ---------------- main: per (b, 32-row tile): D = X Wd^T ; out = X + (gD) U -
__global__ __launch_bounds__(256) void moe_main_kernel(
    const float* __restrict__ x, const float* __restrict__ ldown,
    const float* __restrict__ lup, const float* __restrict__ gws,
    float* __restrict__ out)
{
  constexpr int LT = 32;        // rows per block
  constexpr int KC = 64;        // k-chunk
  constexpr int XW = KC + 4;    // pad: lane stride 68 floats -> <=2-way bank alias (free)
  constexpr int DW = 36;        // D row pad, 144B (16B-aligned rows)

  __shared__ alignas(16) float xs[LT][XW];
  __shared__ alignas(16) float wsm[32][XW];
  __shared__ alignas(16) float dsm[LT][DW];

  const int t  = threadIdx.x;
  const int tx = t & 15;        // pair dim (2 pairs/thread)
  const int ty = t >> 4;        // row dim  (2 rows/thread)
  const int b  = blockIdx.x >> 4;
  const int l0 = (blockIdx.x & 15) * LT;

  const float g0 = gws[b * 4 + 0];
  const float g1 = gws[b * 4 + 1];
  const int   e0 = ((const int*)gws)[b * 4 + 2];
  const int   e1 = ((const int*)gws)[b * 4 + 3];

  const float* xb = x + ((size_t)b * L_ + l0) * H_;

  float a00 = 0.f, a01 = 0.f, a10 = 0.f, a11 = 0.f;

  // -------- Phase A: D[32 rows][32 pairs] over H in chunks of 64 ----------
  for (int k0 = 0; k0 < H_; k0 += KC) {
#pragma unroll
    for (int i = 0; i < 2; ++i) {           // 512 float4 of X-tile
      int f = t + i * 256;
      int row = f >> 4, c4 = (f & 15) << 2;
      *(float4*)&xs[row][c4] = *(const float4*)(xb + (size_t)row * H_ + k0 + c4);
    }
#pragma unroll
    for (int i = 0; i < 2; ++i) {           // 512 float4 of W-tile (pairs)
      int f = t + i * 256;
      int p = f >> 4, c4 = (f & 15) << 2;
      int e = (p < 16) ? e0 : e1;
      int r = p & 15;
      *(float4*)&wsm[p][c4] = *(const float4*)(ldown + ((size_t)e * R_ + r) * H_ + k0 + c4);
    }
    __syncthreads();
#pragma unroll
    for (int kk = 0; kk < KC; kk += 4) {
      float4 xa = *(const float4*)&xs[ty][kk];
      float4 xc = *(const float4*)&xs[ty + 16][kk];
      float4 w0 = *(const float4*)&wsm[tx][kk];
      float4 w1 = *(const float4*)&wsm[tx + 16][kk];
      a00 += xa.x * w0.x + xa.y * w0.y + xa.z * w0.z + xa.w * w0.w;
      a01 += xa.x * w1.x + xa.y * w1.y + xa.z * w1.z + xa.w * w1.w;
      a10 += xc.x * w0.x + xc.y * w0.y + xc.z * w0.z + xc.w * w0.w;
      a11 += xc.x * w1.x + xc.y * w1.y + xc.z * w1.z + xc.w * w1.w;
    }
    __syncthreads();
  }

  // gates folded into D
  dsm[ty][tx]           = a00 * g0;
  dsm[ty][tx + 16]      = a01 * g1;
  dsm[ty + 16][tx]      = a10 * g0;
  dsm[ty + 16][tx + 16] = a11 * g1;
  __syncthreads();

  // -------- Phase B: out[l][h] = x[l][h] + sum_p D[l][p] * U[p][h] --------
  float* outb = out + ((size_t)b * L_ + l0) * H_;
#pragma unroll 1
  for (int hc = 0; hc < H_; hc += 256) {
    const int h = hc + t;
    const float4* u0p = (const float4*)(lup + ((size_t)e0 * H_ + h) * R_);
    const float4* u1p = (const float4*)(lup + ((size_t)e1 * H_ + h) * R_);
    float4 u0[4] = {u0p[0], u0p[1], u0p[2], u0p[3]};
    float4 u1[4] = {u1p[0], u1p[1], u1p[2], u1p[3]};
#pragma unroll 2
    for (int l = 0; l < LT; ++l) {
      const float4* dp = (const float4*)&dsm[l][0];   // broadcast reads
      float4 d0 = dp[0], d1 = dp[1], d2 = dp[2], d3 = dp[3];
      float4 d4 = dp[4], d5 = dp[5], d6 = dp[6], d7 = dp[7];
      float p0 = d0.x * u0[0].x + d0.y * u0[0].y + d0.z * u0[0].z + d0.w * u0[0].w
               + d1.x * u0[1].x + d1.y * u0[1].y + d1.z * u0[1].z + d1.w * u0[1].w;
      float p1 = d2.x * u0[2].x + d2.y * u0[2].y + d2.z * u0[2].z + d2.w * u0[2].w
               + d3.x * u0[3].x + d3.y * u0[3].y + d3.z * u0[3].z + d3.w * u0[3].w;
      float p2 = d4.x * u1[0].x + d4.y * u1[0].y + d4.z * u1[0].z + d4.w * u1[0].w
               + d5.x * u1[1].x + d5.y * u1[1].y + d5.z * u1[1].z + d5.w * u1[1].w;
      float p3 = d6.x * u1[2].x + d6.y * u1[2].y + d6.z * u1[2].z + d6.w * u1[2].w
               + d7.x * u1[3].x + d7.y * u1[3].y + d7.z * u1[3].z + d7.w * u1[3].w;
      outb[(size_t)l * H_ + h] = xb[(size_t)l * H_ + h] + ((p0 + p1) + (p2 + p3));
    }
  }
}

extern "C" void kernel_launch(void* const* d_in, const int* in_sizes, int n_in,
                              void* d_out, int out_size, void* d_ws, size_t ws_size,
                              hipStream_t stream) {
  const float* x  = (const float*)d_in[0];
  const float* rw = (const float*)d_in[1];
  const float* ld = (const float*)d_in[2];
  const float* lu = (const float*)d_in[3];
  float* outp = (float*)d_out;
  float* gws  = (float*)d_ws;   // 32 * 4 floats: g0, g1, e0(int), e1(int)

  hipLaunchKernelGGL(moe_gates_kernel, dim3(B_), dim3(256), 0, stream, x, rw, gws);
  hipLaunchKernelGGL(moe_main_kernel, dim3(B_ * (L_ / 32)), dim3(256), 0, stream,
                     x, ld, lu, gws, outp);
}

// Round 3
// 54.134 us; speedup vs baseline: 1.4742x; 1.4742x over previous
//
#include <hip/hip_runtime.h>
#include <hip/hip_bf16.h>

#define B_ 32
#define L_ 512
#define H_ 1024
#define E_ 8
#define R_ 16

typedef float f32x4 __attribute__((ext_vector_type(4)));
typedef __bf16 bf16x8 __attribute__((ext_vector_type(8)));

static __device__ __forceinline__ __bf16 f2b(float f) { return (__bf16)f; }

// ---------------- gates: logits = x[:,0,:] @ router_w^T ; top-2 softmax ----
__global__ __launch_bounds__(256) void moe_gates_kernel(
    const float* __restrict__ x, const float* __restrict__ rw,
    float* __restrict__ gws)
{
  const int b = blockIdx.x;
  const int t = threadIdx.x;
  const int e = t >> 5;        // 8 experts
  const int s = t & 31;        // 32 lanes per expert
  const float* cls = x + (size_t)b * L_ * H_;   // x[b,0,:]
  const float* w   = rw + (size_t)e * H_;
  float p = 0.f;
  for (int h = s; h < H_; h += 32) p += cls[h] * w[h];
#pragma unroll
  for (int off = 16; off; off >>= 1) p += __shfl_down(p, off, 32);
  __shared__ float logits[E_];
  if (s == 0) logits[e] = p;
  __syncthreads();
  if (t == 0) {
    float m0 = -1e30f; int i0 = 0;
    for (int j = 0; j < E_; ++j) { if (logits[j] > m0) { m0 = logits[j]; i0 = j; } }
    float m1 = -1e30f; int i1 = 0;
    for (int j = 0; j < E_; ++j) { if (j != i0 && logits[j] > m1) { m1 = logits[j]; i1 = j; } }
    float eb = expf(m1 - m0);
    float inv = 1.f / (1.f + eb);
    gws[b * 4 + 0] = inv;          // gate for expert i0
    gws[b * 4 + 1] = eb * inv;     // gate for expert i1
    ((int*)gws)[b * 4 + 2] = i0;
    ((int*)gws)[b * 4 + 3] = i1;
  }
}

// ---- main: per (b, 16-row tile): D = X Wd^T (MFMA) ; out = x + (gD) U (MFMA,
//      residual folded into the C operand from the LDS-resident f32 X tile) --
__global__ __launch_bounds__(256) void moe_main_kernel(
    const float* __restrict__ x, const float* __restrict__ ldown,
    const float* __restrict__ lup, const float* __restrict__ gws,
    float* __restrict__ out)
{
  constexpr int LT = 16;       // rows per block
  constexpr int XP = 1028;     // padded X row stride (f32): 2-way bank alias max

  __shared__ alignas(16) float xs[LT][XP];        // 64.25 KB, f32 (exact residual)
  __shared__ alignas(16) f32x4 red[4][2][64];     // 8 KB cross-wave K reduction
  __shared__ __bf16 dg[16][40];                   // gated D, bf16, padded

  const int t    = threadIdx.x;
  const int w    = t >> 6;
  const int lane = t & 63;
  const int gq   = lane >> 4;    // 0..3
  const int r16  = lane & 15;

  const int b  = blockIdx.x >> 5;
  const int l0 = (blockIdx.x & 31) * LT;

  const float g0 = gws[b * 4 + 0];
  const float g1 = gws[b * 4 + 1];
  const int   e0 = ((const int*)gws)[b * 4 + 2];
  const int   e1 = ((const int*)gws)[b * 4 + 3];

  const float* xb = x + ((size_t)b * L_ + l0) * H_;

  // ---- stage X tile once (f32, coalesced 256B per 16-lane group) ----------
  {
    const int row = t >> 4;
    const int c0  = (t & 15) * 4;
#pragma unroll
    for (int i = 0; i < 16; ++i) {
      const int c = c0 + i * 64;
      *(float4*)&xs[row][c] = *(const float4*)(xb + (size_t)row * H_ + c);
    }
  }
  __syncthreads();

  // ---- Phase A: D[16][32] = X(16xK) * Wd^T, K split across 4 waves --------
  const float* w0p = ldown + (size_t)(e0 * R_ + r16) * H_;   // B-frag n = r16
  const float* w1p = ldown + (size_t)(e1 * R_ + r16) * H_;

  f32x4 acc0 = {0.f, 0.f, 0.f, 0.f};
  f32x4 acc1 = {0.f, 0.f, 0.f, 0.f};

#pragma unroll 4
  for (int s = 0; s < 8; ++s) {
    const int kb = w * 256 + s * 32;
    const int kl = kb + 4 * gq;         // k of elems 0..3
    const int kh = kl + 16;             // k of elems 4..7
    float4 xlo = *(const float4*)&xs[r16][kl];
    float4 xhi = *(const float4*)&xs[r16][kh];
    float4 alo = *(const float4*)(w0p + kl);
    float4 ahi = *(const float4*)(w0p + kh);
    float4 blo = *(const float4*)(w1p + kl);
    float4 bhi = *(const float4*)(w1p + kh);
    bf16x8 af  = { f2b(xlo.x), f2b(xlo.y), f2b(xlo.z), f2b(xlo.w),
                   f2b(xhi.x), f2b(xhi.y), f2b(xhi.z), f2b(xhi.w) };
    bf16x8 bf0 = { f2b(alo.x), f2b(alo.y), f2b(alo.z), f2b(alo.w),
                   f2b(ahi.x), f2b(ahi.y), f2b(ahi.z), f2b(ahi.w) };
    bf16x8 bf1 = { f2b(blo.x), f2b(blo.y), f2b(blo.z), f2b(blo.w),
                   f2b(bhi.x), f2b(bhi.y), f2b(bhi.z), f2b(bhi.w) };
    acc0 = __builtin_amdgcn_mfma_f32_16x16x32_bf16(af, bf0, acc0, 0, 0, 0);
    acc1 = __builtin_amdgcn_mfma_f32_16x16x32_bf16(af, bf1, acc1, 0, 0, 0);
  }

  red[w][0][lane] = acc0;
  red[w][1][lane] = acc1;
  __syncthreads();

  // ---- cross-wave reduce + gate fold + bf16 pack of D ---------------------
  if (t < 128) {
    const int tile = t >> 6;            // 0: expert e0 pairs, 1: expert e1
    const int slot = t & 63;
    f32x4 v = red[0][tile][slot];
    v += red[1][tile][slot];
    v += red[2][tile][slot];
    v += red[3][tile][slot];
    const float g = tile ? g1 : g0;
    const int p  = tile * 16 + (slot & 15);   // C/D: col = lane&15
    const int r0 = (slot >> 4) * 4;           // C/D: row = 4*(lane>>4)+j
#pragma unroll
    for (int j = 0; j < 4; ++j) dg[r0 + j][p] = f2b(v[j] * g);
  }
  __syncthreads();

  // ---- Phase B: out[16][1024] = x + Dg(16x32) * Up(32x1024) ---------------
  bf16x8 dfrag;
  {
    const int kl = 4 * gq;
#pragma unroll
    for (int j = 0; j < 4; ++j) {
      dfrag[j]     = dg[r16][kl + j];
      dfrag[4 + j] = dg[r16][16 + kl + j];
    }
  }

  const float* u0b = lup + (size_t)e0 * H_ * R_;
  const float* u1b = lup + (size_t)e1 * H_ * R_;
  float* outb = out + ((size_t)b * L_ + l0) * H_;

#pragma unroll 4
  for (int nt = 0; nt < 16; ++nt) {
    const int h = w * 256 + nt * 16 + r16;     // B-frag col = r16
    float4 ulo = *(const float4*)(u0b + (size_t)h * R_ + 4 * gq);   // k = 4gq+j
    float4 uhi = *(const float4*)(u1b + (size_t)h * R_ + 4 * gq);   // k = 16+4gq+j
    bf16x8 uf = { f2b(ulo.x), f2b(ulo.y), f2b(ulo.z), f2b(ulo.w),
                  f2b(uhi.x), f2b(uhi.y), f2b(uhi.z), f2b(uhi.w) };
    f32x4 acc;
#pragma unroll
    for (int j = 0; j < 4; ++j) acc[j] = xs[4 * gq + j][h];          // residual
    acc = __builtin_amdgcn_mfma_f32_16x16x32_bf16(dfrag, uf, acc, 0, 0, 0);
#pragma unroll
    for (int j = 0; j < 4; ++j) outb[(size_t)(4 * gq + j) * H_ + h] = acc[j];
  }
}

extern "C" void kernel_launch(void* const* d_in, const int* in_sizes, int n_in,
                              void* d_out, int out_size, void* d_ws, size_t ws_size,
                              hipStream_t stream) {
  const float* x  = (const float*)d_in[0];
  const float* rw = (const float*)d_in[1];
  const float* ld = (const float*)d_in[2];
  const float* lu = (const float*)d_in[3];
  float* outp = (float*)d_out;
  float* gws  = (float*)d_ws;   // 32 * {g0, g1, e0(int), e1(int)}

  hipLaunchKernelGGL(moe_gates_kernel, dim3(B_), dim3(256), 0, stream, x, rw, gws);
  hipLaunchKernelGGL(moe_main_kernel, dim3(B_ * (L_ / 16)), dim3(256), 0, stream,
                     x, ld, lu, gws, outp);
}